// Round 3
// baseline (49.923 us; speedup 1.0000x reference)
//
#include <hip/hip_runtime.h>

// FuseSliceTogetherReplacement:
//   input_tensor: (4096, 1024) f32
//   slices_index: (256,) int32 in [0, 960)
//   slice_len:    64
//   out[s, r, j] = input[r, slices_index[s] + j]   -> shape (256, 4096, 64) f32
//
// Memory-bound: 256 MiB written (write-once -> nontemporal stores),
// input (16 MiB) is L2/L3-resident with ~17x reuse.
// One thread per output float4; writes are 16B-aligned and fully coalesced.
// Reads are 4 scalar dwords (slice start has arbitrary alignment) hitting L2.

#define ROWS    4096
#define IN_COLS 1024
#define N_SLICE 256
#define SLEN    64

// __builtin_nontemporal_store needs a NATIVE vector type, not HIP's float4
// class (compile error last round). ext_vector_type(4) of float lowers to one
// global_store_dwordx4 with the nt flag.
typedef float f32x4 __attribute__((ext_vector_type(4)));

__global__ __launch_bounds__(256)
void fuse_slice_gather_kernel(const float* __restrict__ in,
                              const int* __restrict__ idx,
                              f32x4* __restrict__ out4) {
    // One f32x4 per thread. Total = 256 * 4096 * 16 = 16,777,216.
    unsigned g  = blockIdx.x * 256u + threadIdx.x;
    unsigned j4 = g & 15u;                 // which float4 within the 64-wide slice
    unsigned r  = (g >> 4) & (ROWS - 1u);  // row
    unsigned s  = g >> 16;                 // slice (wave-uniform: 65536 threads/slice)

    int c0 = idx[s];                       // wave-uniform load, L1/L2-hit
    const float* __restrict__ src = in + (size_t)r * IN_COLS + (unsigned)c0 + j4 * 4u;

    f32x4 v;
    v.x = src[0];
    v.y = src[1];
    v.z = src[2];
    v.w = src[3];

    // Output is streamed once and never re-read: nontemporal store keeps the
    // 256 MiB stream from evicting the cache-resident 16 MiB input in L2.
    __builtin_nontemporal_store(v, &out4[g]);
}

extern "C" void kernel_launch(void* const* d_in, const int* in_sizes, int n_in,
                              void* d_out, int out_size, void* d_ws, size_t ws_size,
                              hipStream_t stream) {
    const float* in  = (const float*)d_in[0];
    const int*   idx = (const int*)d_in[1];
    // d_in[2] is slice_len == 64, compile-time constant here.
    f32x4* out4 = (f32x4*)d_out;

    // 256 slices * 4096 rows * 16 float4 = 16,777,216 threads / 256 = 65,536 blocks
    dim3 grid(N_SLICE * ROWS * (SLEN / 4) / 256);
    dim3 block(256);
    fuse_slice_gather_kernel<<<grid, block, 0, stream>>>(in, idx, out4);
}

// Round 7
// 48.978 us; speedup vs baseline: 1.0193x; 1.0193x over previous
//
#include <hip/hip_runtime.h>

// FuseSliceTogetherReplacement:
//   out[s, r, j] = input[r, slices_index[s] + j], input (4096,1024) f32,
//   256 slices of len 64 -> out (256, 4096, 64) f32.
//
// Write-BW-bound: 256 MiB streamed out (nontemporal), 16 MiB input is
// L2-resident with ~17x reuse.
//
// R4 refinement: 4 f32x4 per thread in block-contiguous 16 KiB chunks.
//  - 65536 f32x4 per slice % 1024 f32x4 per block == 0  ->  slice id is
//    BLOCK-UNIFORM (s = blockIdx.x >> 6): idx[s] becomes one s_load per block.
//  - all 16 gather dwords issue before the 4 nt stores -> 4x MLP per wave.

#define ROWS    4096
#define IN_COLS 1024
#define N_SLICE 256
#define SLEN    64

typedef float f32x4 __attribute__((ext_vector_type(4)));

__global__ __launch_bounds__(256)
void fuse_slice_gather_kernel(const float* __restrict__ in,
                              const int* __restrict__ idx,
                              f32x4* __restrict__ out4) {
    // Block handles 1024 consecutive f32x4 (16 KiB of output).
    unsigned base = blockIdx.x * 1024u + threadIdx.x;  // first f32x4 index
    unsigned s    = blockIdx.x >> 6;                   // 64 blocks per slice — uniform
    int c0 = idx[s];                                   // scalar load (block-uniform)

    f32x4 v[4];
#pragma unroll
    for (int k = 0; k < 4; ++k) {
        unsigned pos = base + (unsigned)k * 256u;
        unsigned j4  = pos & 15u;                 // float4 within the 64-wide slice
        unsigned r   = (pos >> 4) & (ROWS - 1u);  // row
        const float* __restrict__ src =
            in + (size_t)r * IN_COLS + (unsigned)c0 + j4 * 4u;
        v[k].x = src[0];
        v[k].y = src[1];
        v[k].z = src[2];
        v[k].w = src[3];
    }

#pragma unroll
    for (int k = 0; k < 4; ++k) {
        // Output written once, never re-read: nt store avoids L2 write-allocate
        // churn against the cache-resident input.
        __builtin_nontemporal_store(v[k], &out4[base + (unsigned)k * 256u]);
    }
}

extern "C" void kernel_launch(void* const* d_in, const int* in_sizes, int n_in,
                              void* d_out, int out_size, void* d_ws, size_t ws_size,
                              hipStream_t stream) {
    const float* in  = (const float*)d_in[0];
    const int*   idx = (const int*)d_in[1];
    // d_in[2] is slice_len == 64, compile-time constant here.
    f32x4* out4 = (f32x4*)d_out;

    // 16,777,216 f32x4 total / 1024 per block = 16384 blocks.
    dim3 grid(N_SLICE * ROWS * (SLEN / 4) / 1024);
    dim3 block(256);
    fuse_slice_gather_kernel<<<grid, block, 0, stream>>>(in, idx, out4);
}